// Round 1
// baseline (1302.974 us; speedup 1.0000x reference)
//
#include <hip/hip_runtime.h>

typedef unsigned short u16;
typedef __attribute__((ext_vector_type(4))) float f32x4;
typedef __attribute__((ext_vector_type(8))) short s16x8;

#define DEV __device__ __forceinline__

// Problem constants
constexpr int Bb = 64, Tt = 2048, Dd = 1024, Cc = 1024, Ff = 256;
constexpr int TP = Tt + 4;            // padded time (2 halo rows each side)
constexpr int M1 = Bb * Tt;           // 131072

DEV u16 f2bf(float f) {               // RNE f32 -> bf16
    union { float f; unsigned u; } v; v.f = f;
    unsigned r = v.u + 0x7fffu + ((v.u >> 16) & 1u);
    return (u16)(r >> 16);
}

// ---------------- K0: l2-normalize label rows, cast bf16 ----------------
__global__ __launch_bounds__(256) void k_label_norm(const float* __restrict__ L,
                                                    u16* __restrict__ Ln) {
    int c = blockIdx.x;               // 1024 rows
    int t = threadIdx.x;
    const float* row = L + (size_t)c * Dd;
    float s = 0.f;
    for (int d = t; d < Dd; d += 256) { float v = row[d]; s += v * v; }
    for (int o = 32; o; o >>= 1) s += __shfl_down(s, o);
    __shared__ float red[4];
    if ((t & 63) == 0) red[t >> 6] = s;
    __syncthreads();
    float tot = red[0] + red[1] + red[2] + red[3];
    float r = rsqrtf(fmaxf(tot, 1e-12f));
    for (int d = t; d < Dd; d += 256) Ln[(size_t)c * Dd + d] = f2bf(row[d] * r);
}

// ---------------- K0b: transpose conv_w (K,C,F) f32 -> Wt (K,F,C) bf16 --
__global__ __launch_bounds__(256) void k_wt(const float* __restrict__ W,
                                            u16* __restrict__ Wt) {
    __shared__ float tile[64][65];
    int k = blockIdx.x; int c0 = blockIdx.y * 64; int f0 = blockIdx.z * 64;
    int tid = threadIdx.x;
    const float* Wk = W + (size_t)k * Cc * Ff;
    #pragma unroll
    for (int i = 0; i < 16; ++i) {
        int q = tid + i * 256;
        int ci = q >> 6, fj = q & 63;
        tile[ci][fj] = Wk[(size_t)(c0 + ci) * Ff + f0 + fj];
    }
    __syncthreads();
    #pragma unroll
    for (int i = 0; i < 16; ++i) {
        int q = tid + i * 256;
        int fi = q >> 6, cj = q & 63;
        Wt[((size_t)k * Ff + f0 + fi) * Cc + c0 + cj] = f2bf(tile[cj][fi]);
    }
}

// ---------------- K1: zero the halo rows of padded G ----------------
__global__ __launch_bounds__(256) void k_zpad(u16* __restrict__ Gp) {
    int b_ = blockIdx.x, tid = threadIdx.x;
    size_t base = (size_t)b_ * TP * Cc;
    for (int i = tid; i < 2 * Cc; i += 256) {
        Gp[base + i] = 0;                               // rows 0,1
        Gp[base + (size_t)(TP - 2) * Cc + i] = 0;       // rows TP-2, TP-1
    }
}

// ---------------- K2: G = S(f32) @ Ln^T  -> Gp bf16 (padded rows) -------
// 128x128 tile, BK=64, 4 waves (2x2), mfma 16x16x32 bf16.
__global__ __launch_bounds__(256) void k_gemm1(const float* __restrict__ S,
                                               const u16* __restrict__ Ln,
                                               u16* __restrict__ Gp) {
    __shared__ alignas(16) u16 As[128 * 64];
    __shared__ alignas(16) u16 Bs[128 * 64];
    int bid = blockIdx.x;
    int mt = bid >> 3, nt = bid & 7;
    const int m0 = mt * 128, n0 = nt * 128;
    int tid = threadIdx.x;
    int lane = tid & 63, wid = tid >> 6;
    int wm = wid >> 1, wn = wid & 1;
    f32x4 acc[4][4] = {};

    for (int kt = 0; kt < 16; ++kt) {
        int k0 = kt * 64;
        // stage A: 128x64 f32 -> bf16, 8 float4 per thread
        #pragma unroll
        for (int i = 0; i < 8; ++i) {
            int q = tid + i * 256;
            int row = q >> 4, c4 = (q & 15) * 4;
            f32x4 v = *(const f32x4*)(S + (size_t)(m0 + row) * Dd + k0 + c4);
            u16 h0 = f2bf(v.x), h1 = f2bf(v.y), h2 = f2bf(v.z), h3 = f2bf(v.w);
            u16* p = &As[row * 64 + c4];
            p[0] = h0; p[1] = h1; p[2] = h2; p[3] = h3;
        }
        // stage B: 128x64 bf16, 4 x 16B per thread
        #pragma unroll
        for (int i = 0; i < 4; ++i) {
            int q = tid + i * 256;
            int row = q >> 3, c8 = (q & 7) * 8;
            *(s16x8*)&Bs[row * 64 + c8] =
                *(const s16x8*)(Ln + (size_t)(n0 + row) * Dd + k0 + c8);
        }
        __syncthreads();
        #pragma unroll
        for (int kk = 0; kk < 2; ++kk) {
            int rsel = lane & 15, ksel = kk * 32 + (lane >> 4) * 8;
            s16x8 a[4], b[4];
            #pragma unroll
            for (int f = 0; f < 4; ++f)
                a[f] = *(const s16x8*)&As[(wm * 64 + f * 16 + rsel) * 64 + ksel];
            #pragma unroll
            for (int f = 0; f < 4; ++f)
                b[f] = *(const s16x8*)&Bs[(wn * 64 + f * 16 + rsel) * 64 + ksel];
            #pragma unroll
            for (int fm = 0; fm < 4; ++fm)
                #pragma unroll
                for (int fn = 0; fn < 4; ++fn)
                    acc[fm][fn] = __builtin_amdgcn_mfma_f32_16x16x32_bf16(
                        a[fm], b[fn], acc[fm][fn], 0, 0, 0);
        }
        __syncthreads();
    }
    // epilogue: write bf16 into padded G
    #pragma unroll
    for (int fm = 0; fm < 4; ++fm) {
        #pragma unroll
        for (int r = 0; r < 4; ++r) {
            int row = m0 + wm * 64 + fm * 16 + (lane >> 4) * 4 + r;
            int b_ = row >> 11, t = row & 2047;
            size_t base = ((size_t)b_ * TP + t + 2) * Cc;
            #pragma unroll
            for (int fn = 0; fn < 4; ++fn) {
                int col = n0 + wn * 64 + fn * 16 + (lane & 15);
                Gp[base + col] = f2bf(acc[fm][fn][r]);
            }
        }
    }
}

// ---------------- K3: conv1d(K=5) as GEMM + relu + max_f -> att_v -------
// BM=128 (one batch, 2048%128==0), BN=256 (full F), 8 waves (2x4).
__global__ __launch_bounds__(512) void k_conv(const u16* __restrict__ Gp,
                                              const u16* __restrict__ Wt,
                                              const float* __restrict__ bias,
                                              float* __restrict__ att) {
    __shared__ alignas(16) u16 As[132 * 64];
    __shared__ alignas(16) u16 Bs[256 * 64];
    __shared__ float red[4][128];
    int mt = blockIdx.x;                 // 1024 tiles
    int b_ = mt >> 4;                    // 16 tiles per batch
    int t0 = (mt & 15) * 128;
    int tid = threadIdx.x, lane = tid & 63, wid = tid >> 6;
    int wm = wid >> 2, wn = wid & 3;
    f32x4 acc[4][4] = {};
    const size_t gbase = ((size_t)b_ * TP + t0) * Cc;  // padded row t0+0

    for (int ct = 0; ct < 16; ++ct) {
        int c0 = ct * 64;
        // stage A once per c-chunk: 132 rows x 64 cols bf16
        #pragma unroll
        for (int i = 0; i < 3; ++i) {
            int q = tid + i * 512;
            if (q < 1056) {
                int row = q >> 3, c8 = (q & 7) * 8;
                *(s16x8*)&As[row * 64 + c8] =
                    *(const s16x8*)(Gp + gbase + (size_t)row * Cc + c0 + c8);
            }
        }
        for (int k = 0; k < 5; ++k) {
            // stage B: Wt[k] 256x64
            #pragma unroll
            for (int i = 0; i < 4; ++i) {
                int q = tid + i * 512;
                int row = q >> 3, c8 = (q & 7) * 8;
                *(s16x8*)&Bs[row * 64 + c8] =
                    *(const s16x8*)(Wt + ((size_t)k * Ff + row) * Cc + c0 + c8);
            }
            __syncthreads();
            #pragma unroll
            for (int kk = 0; kk < 2; ++kk) {
                int rsel = lane & 15, ksel = kk * 32 + (lane >> 4) * 8;
                s16x8 a[4], b[4];
                #pragma unroll
                for (int f = 0; f < 4; ++f)
                    a[f] = *(const s16x8*)&As[(k + wm * 64 + f * 16 + rsel) * 64 + ksel];
                #pragma unroll
                for (int f = 0; f < 4; ++f)
                    b[f] = *(const s16x8*)&Bs[(wn * 64 + f * 16 + rsel) * 64 + ksel];
                #pragma unroll
                for (int fm = 0; fm < 4; ++fm)
                    #pragma unroll
                    for (int fn = 0; fn < 4; ++fn)
                        acc[fm][fn] = __builtin_amdgcn_mfma_f32_16x16x32_bf16(
                            a[fm], b[fn], acc[fm][fn], 0, 0, 0);
            }
            __syncthreads();
        }
    }
    // epilogue: relu(acc+bias), max over all 256 filters -> att_v
    float bv[4];
    #pragma unroll
    for (int fn = 0; fn < 4; ++fn)
        bv[fn] = bias[wn * 64 + fn * 16 + (lane & 15)];
    #pragma unroll
    for (int fm = 0; fm < 4; ++fm) {
        #pragma unroll
        for (int r = 0; r < 4; ++r) {
            float v = 0.f;
            #pragma unroll
            for (int fn = 0; fn < 4; ++fn)
                v = fmaxf(v, fmaxf(acc[fm][fn][r] + bv[fn], 0.f));
            #pragma unroll
            for (int m = 1; m <= 8; m <<= 1) v = fmaxf(v, __shfl_xor(v, m));
            if ((lane & 15) == 0)
                red[wn][wm * 64 + fm * 16 + (lane >> 4) * 4 + r] = v;
        }
    }
    __syncthreads();
    if (tid < 128) {
        float v = fmaxf(fmaxf(red[0][tid], red[1][tid]),
                        fmaxf(red[2][tid], red[3][tid]));
        att[(size_t)mt * 128 + tid] = v;
    }
}

// ---------------- K4: H partials: part[tc][b][d] = sum_t S*att ----------
__global__ __launch_bounds__(256) void k_henc(const float* __restrict__ S,
                                              const float* __restrict__ att,
                                              float* __restrict__ part) {
    int b_ = blockIdx.x, tc = blockIdx.y;
    int tid = threadIdx.x;
    int d = tid * 4;
    const float* Sp = S + ((size_t)b_ * Tt + (size_t)tc * 256) * Dd + d;
    const float* ap = att + (size_t)b_ * Tt + (size_t)tc * 256;
    f32x4 acc = {};
    for (int t = 0; t < 256; ++t) {
        float a = ap[t];
        f32x4 s = *(const f32x4*)(Sp + (size_t)t * Dd);
        acc += s * a;
    }
    *(f32x4*)(part + ((size_t)tc * Bb + b_) * Dd + d) = acc;
}

// ---------------- K5: reduce 8 partials -> d_out ----------------
__global__ __launch_bounds__(256) void k_hred(const float* __restrict__ part,
                                              float* __restrict__ out) {
    int i = blockIdx.x * 256 + threadIdx.x;   // 65536 outputs
    float s = 0.f;
    #pragma unroll
    for (int p = 0; p < 8; ++p) s += part[(size_t)p * (Bb * Dd) + i];
    out[i] = s;
}

extern "C" void kernel_launch(void* const* d_in, const int* in_sizes, int n_in,
                              void* d_out, int out_size, void* d_ws, size_t ws_size,
                              hipStream_t stream) {
    const float* S  = (const float*)d_in[0];
    const float* L  = (const float*)d_in[1];
    const float* W  = (const float*)d_in[2];
    const float* cb = (const float*)d_in[3];
    float* out = (float*)d_out;
    char* ws = (char*)d_ws;

    // workspace layout (bytes)
    const size_t GP_B  = (size_t)Bb * TP * Cc * 2;      // 268,959,744
    const size_t LN_B  = (size_t)Cc * Dd * 2;           //   2,097,152
    const size_t WT_B  = (size_t)5 * Ff * Cc * 2;       //   2,621,440
    const size_t ATT_B = (size_t)M1 * 4;                //     524,288
    u16*   Gp   = (u16*)(ws);
    u16*   Ln   = (u16*)(ws + GP_B);
    u16*   Wt   = (u16*)(ws + GP_B + LN_B);
    float* att  = (float*)(ws + GP_B + LN_B + WT_B);
    float* part = (float*)(ws + GP_B + LN_B + WT_B + ATT_B);

    k_label_norm<<<Cc, 256, 0, stream>>>(L, Ln);
    k_wt<<<dim3(5, Cc / 64, Ff / 64), 256, 0, stream>>>(W, Wt);
    k_zpad<<<Bb, 256, 0, stream>>>(Gp);
    k_gemm1<<<(M1 / 128) * (Cc / 128), 256, 0, stream>>>(S, Ln, Gp);
    k_conv<<<M1 / 128, 512, 0, stream>>>(Gp, Wt, cb, att);
    k_henc<<<dim3(Bb, 8), 256, 0, stream>>>(S, att, part);
    k_hred<<<(Bb * Dd) / 256, 256, 0, stream>>>(part, out);
}

// Round 2
// 1254.254 us; speedup vs baseline: 1.0388x; 1.0388x over previous
//
#include <hip/hip_runtime.h>

typedef unsigned short u16;
typedef __attribute__((ext_vector_type(4))) float f32x4;
typedef __attribute__((ext_vector_type(8))) short s16x8;
typedef __attribute__((ext_vector_type(4))) unsigned short u16x4;

#define DEV __device__ __forceinline__

// Problem constants
constexpr int Bb = 64, Tt = 2048, Dd = 1024, Cc = 1024, Ff = 256;
constexpr int TP = Tt + 4;            // padded time (2 halo rows each side)
constexpr int M1 = Bb * Tt;           // 131072

DEV u16 f2bf(float f) {               // RNE f32 -> bf16
    union { float f; unsigned u; } v; v.f = f;
    unsigned r = v.u + 0x7fffu + ((v.u >> 16) & 1u);
    return (u16)(r >> 16);
}
DEV float bf2f(u16 h) {
    union { unsigned u; float f; } v; v.u = ((unsigned)h) << 16; return v.f;
}

// async global->LDS, 16B per lane. lds dest must be wave-uniform base;
// HW writes lane l at base + l*16.
DEV void gl_lds16(const u16* g, u16* l) {
    __builtin_amdgcn_global_load_lds(
        (const __attribute__((address_space(1))) unsigned*)(const void*)g,
        (__attribute__((address_space(3))) unsigned*)(void*)l,
        16, 0, 0);
}

// ---------------- K-1: S f32 -> bf16 ----------------
__global__ __launch_bounds__(256) void k_s2bf(const float* __restrict__ S,
                                              u16* __restrict__ Sb) {
    size_t i = ((size_t)blockIdx.x * 256 + threadIdx.x) * 8;
    const size_t stride = (size_t)gridDim.x * 256 * 8;
    const size_t n = (size_t)M1 * Dd;
    for (; i < n; i += stride) {
        f32x4 a = *(const f32x4*)(S + i);
        f32x4 b = *(const f32x4*)(S + i + 4);
        s16x8 r;
        r[0] = (short)f2bf(a.x); r[1] = (short)f2bf(a.y);
        r[2] = (short)f2bf(a.z); r[3] = (short)f2bf(a.w);
        r[4] = (short)f2bf(b.x); r[5] = (short)f2bf(b.y);
        r[6] = (short)f2bf(b.z); r[7] = (short)f2bf(b.w);
        *(s16x8*)(Sb + i) = r;
    }
}

// ---------------- K0: l2-normalize label rows, cast bf16 ----------------
__global__ __launch_bounds__(256) void k_label_norm(const float* __restrict__ L,
                                                    u16* __restrict__ Ln) {
    int c = blockIdx.x;
    int t = threadIdx.x;
    const float* row = L + (size_t)c * Dd;
    float s = 0.f;
    for (int d = t; d < Dd; d += 256) { float v = row[d]; s += v * v; }
    for (int o = 32; o; o >>= 1) s += __shfl_down(s, o);
    __shared__ float red[4];
    if ((t & 63) == 0) red[t >> 6] = s;
    __syncthreads();
    float tot = red[0] + red[1] + red[2] + red[3];
    float r = rsqrtf(fmaxf(tot, 1e-12f));
    for (int d = t; d < Dd; d += 256) Ln[(size_t)c * Dd + d] = f2bf(row[d] * r);
}

// ---------------- K0b: transpose conv_w (K,C,F) f32 -> Wt (K,F,C) bf16 --
__global__ __launch_bounds__(256) void k_wt(const float* __restrict__ W,
                                            u16* __restrict__ Wt) {
    __shared__ float tile[64][65];
    int k = blockIdx.x; int c0 = blockIdx.y * 64; int f0 = blockIdx.z * 64;
    int tid = threadIdx.x;
    const float* Wk = W + (size_t)k * Cc * Ff;
    #pragma unroll
    for (int i = 0; i < 16; ++i) {
        int q = tid + i * 256;
        int ci = q >> 6, fj = q & 63;
        tile[ci][fj] = Wk[(size_t)(c0 + ci) * Ff + f0 + fj];
    }
    __syncthreads();
    #pragma unroll
    for (int i = 0; i < 16; ++i) {
        int q = tid + i * 256;
        int fi = q >> 6, cj = q & 63;
        Wt[((size_t)k * Ff + f0 + fi) * Cc + c0 + cj] = f2bf(tile[cj][fi]);
    }
}

// ---------------- K1: zero the halo rows of padded G ----------------
__global__ __launch_bounds__(256) void k_zpad(u16* __restrict__ Gp) {
    int b_ = blockIdx.x, tid = threadIdx.x;
    size_t base = (size_t)b_ * TP * Cc;
    for (int i = tid; i < 2 * Cc; i += 256) {
        Gp[base + i] = 0;
        Gp[base + (size_t)(TP - 2) * Cc + i] = 0;
    }
}

// ---------------- K2: G = Sb(bf16) @ Ln^T  -> Gp bf16 (padded rows) -----
// 128x128, BK=64, 4 waves (2x2), global_load_lds staging, XCD-chunked grid.
__global__ __launch_bounds__(256) void k_gemm1_bf(const u16* __restrict__ Sb,
                                                  const u16* __restrict__ Ln,
                                                  u16* __restrict__ Gp) {
    __shared__ alignas(16) u16 As[128 * 64];
    __shared__ alignas(16) u16 Bs[128 * 64];
    int bid = blockIdx.x;
    // XCD chunking: xcd = bid&7 gets wgs [xcd*1024, ...): 128 mt x 8 nt, mt-major
    int xcd = bid & 7, idx = bid >> 3;
    int mt = xcd * 128 + (idx >> 3);
    int nt = idx & 7;
    const int m0 = mt * 128, n0 = nt * 128;
    int tid = threadIdx.x;
    int lane = tid & 63, wid = tid >> 6;
    int wm = wid >> 1, wn = wid & 1;
    int srow = lane >> 3;             // staging: lane -> row-in-segment
    int scol = (lane & 7) * 8;        // staging: lane -> col (elements)
    f32x4 acc[4][4] = {};

    for (int kt = 0; kt < 16; ++kt) {
        int k0 = kt * 64;
        #pragma unroll
        for (int i = 0; i < 4; ++i) {
            int seg = wid * 4 + i;    // 0..15, 8 rows each
            int r0 = seg * 8;
            gl_lds16(Sb + (size_t)(m0 + r0 + srow) * Dd + k0 + scol, &As[seg * 512]);
            gl_lds16(Ln + (size_t)(n0 + r0 + srow) * Dd + k0 + scol, &Bs[seg * 512]);
        }
        __syncthreads();
        #pragma unroll
        for (int kk = 0; kk < 2; ++kk) {
            int rsel = lane & 15, ksel = kk * 32 + (lane >> 4) * 8;
            s16x8 a[4], b[4];
            #pragma unroll
            for (int f = 0; f < 4; ++f)
                a[f] = *(const s16x8*)&As[(wm * 64 + f * 16 + rsel) * 64 + ksel];
            #pragma unroll
            for (int f = 0; f < 4; ++f)
                b[f] = *(const s16x8*)&Bs[(wn * 64 + f * 16 + rsel) * 64 + ksel];
            #pragma unroll
            for (int fm = 0; fm < 4; ++fm)
                #pragma unroll
                for (int fn = 0; fn < 4; ++fn)
                    acc[fm][fn] = __builtin_amdgcn_mfma_f32_16x16x32_bf16(
                        a[fm], b[fn], acc[fm][fn], 0, 0, 0);
        }
        __syncthreads();
    }
    #pragma unroll
    for (int fm = 0; fm < 4; ++fm) {
        #pragma unroll
        for (int r = 0; r < 4; ++r) {
            int row = m0 + wm * 64 + fm * 16 + (lane >> 4) * 4 + r;
            int b_ = row >> 11, t = row & 2047;
            size_t base = ((size_t)b_ * TP + t + 2) * Cc;
            #pragma unroll
            for (int fn = 0; fn < 4; ++fn) {
                int col = n0 + wn * 64 + fn * 16 + (lane & 15);
                Gp[base + col] = f2bf(acc[fm][fn][r]);
            }
        }
    }
}

// ---------------- K2-fallback: f32 A path (round-1 kernel + swizzle) ----
__global__ __launch_bounds__(256) void k_gemm1_f32(const float* __restrict__ S,
                                                   const u16* __restrict__ Ln,
                                                   u16* __restrict__ Gp) {
    __shared__ alignas(16) u16 As[128 * 64];
    __shared__ alignas(16) u16 Bs[128 * 64];
    int bid = blockIdx.x;
    int xcd = bid & 7, idx = bid >> 3;
    int mt = xcd * 128 + (idx >> 3);
    int nt = idx & 7;
    const int m0 = mt * 128, n0 = nt * 128;
    int tid = threadIdx.x;
    int lane = tid & 63, wid = tid >> 6;
    int wm = wid >> 1, wn = wid & 1;
    f32x4 acc[4][4] = {};

    for (int kt = 0; kt < 16; ++kt) {
        int k0 = kt * 64;
        #pragma unroll
        for (int i = 0; i < 8; ++i) {
            int q = tid + i * 256;
            int row = q >> 4, c4 = (q & 15) * 4;
            f32x4 v = *(const f32x4*)(S + (size_t)(m0 + row) * Dd + k0 + c4);
            u16* p = &As[row * 64 + c4];
            p[0] = f2bf(v.x); p[1] = f2bf(v.y); p[2] = f2bf(v.z); p[3] = f2bf(v.w);
        }
        #pragma unroll
        for (int i = 0; i < 4; ++i) {
            int q = tid + i * 256;
            int row = q >> 3, c8 = (q & 7) * 8;
            *(s16x8*)&Bs[row * 64 + c8] =
                *(const s16x8*)(Ln + (size_t)(n0 + row) * Dd + k0 + c8);
        }
        __syncthreads();
        #pragma unroll
        for (int kk = 0; kk < 2; ++kk) {
            int rsel = lane & 15, ksel = kk * 32 + (lane >> 4) * 8;
            s16x8 a[4], b[4];
            #pragma unroll
            for (int f = 0; f < 4; ++f)
                a[f] = *(const s16x8*)&As[(wm * 64 + f * 16 + rsel) * 64 + ksel];
            #pragma unroll
            for (int f = 0; f < 4; ++f)
                b[f] = *(const s16x8*)&Bs[(wn * 64 + f * 16 + rsel) * 64 + ksel];
            #pragma unroll
            for (int fm = 0; fm < 4; ++fm)
                #pragma unroll
                for (int fn = 0; fn < 4; ++fn)
                    acc[fm][fn] = __builtin_amdgcn_mfma_f32_16x16x32_bf16(
                        a[fm], b[fn], acc[fm][fn], 0, 0, 0);
        }
        __syncthreads();
    }
    #pragma unroll
    for (int fm = 0; fm < 4; ++fm) {
        #pragma unroll
        for (int r = 0; r < 4; ++r) {
            int row = m0 + wm * 64 + fm * 16 + (lane >> 4) * 4 + r;
            int b_ = row >> 11, t = row & 2047;
            size_t base = ((size_t)b_ * TP + t + 2) * Cc;
            #pragma unroll
            for (int fn = 0; fn < 4; ++fn) {
                int col = n0 + wn * 64 + fn * 16 + (lane & 15);
                Gp[base + col] = f2bf(acc[fm][fn][r]);
            }
        }
    }
}

// ---------------- K3: conv1d(K=5) as GEMM + relu + max_f -> att_v -------
// BM=128, BN=256 (full F), 8 waves (2x4), global_load_lds staging.
__global__ __launch_bounds__(512) void k_conv(const u16* __restrict__ Gp,
                                              const u16* __restrict__ Wt,
                                              const float* __restrict__ bias,
                                              float* __restrict__ att) {
    __shared__ alignas(16) u16 As[136 * 64];   // rows 132..135 = overrun garbage, never consumed
    __shared__ alignas(16) u16 Bs[256 * 64];
    __shared__ float red[4][128];
    int mt = blockIdx.x;
    int b_ = mt >> 4;
    int t0 = (mt & 15) * 128;
    int tid = threadIdx.x, lane = tid & 63, wid = tid >> 6;
    int wm = wid >> 2, wn = wid & 3;
    int srow = lane >> 3, scol = (lane & 7) * 8;
    f32x4 acc[4][4] = {};
    const size_t gbase = ((size_t)b_ * TP + t0) * Cc;

    for (int ct = 0; ct < 16; ++ct) {
        int c0 = ct * 64;
        // A: 17 segments of 8 rows (136 rows incl. 4 garbage)
        for (int s = wid; s < 17; s += 8)
            gl_lds16(Gp + gbase + (size_t)(s * 8 + srow) * Cc + c0 + scol, &As[s * 512]);
        for (int k = 0; k < 5; ++k) {
            #pragma unroll
            for (int i = 0; i < 4; ++i) {
                int seg = wid * 4 + i;    // 0..31
                gl_lds16(Wt + ((size_t)k * Ff + seg * 8 + srow) * Cc + c0 + scol,
                         &Bs[seg * 512]);
            }
            __syncthreads();
            #pragma unroll
            for (int kk = 0; kk < 2; ++kk) {
                int rsel = lane & 15, ksel = kk * 32 + (lane >> 4) * 8;
                s16x8 a[4], b[4];
                #pragma unroll
                for (int f = 0; f < 4; ++f)
                    a[f] = *(const s16x8*)&As[(k + wm * 64 + f * 16 + rsel) * 64 + ksel];
                #pragma unroll
                for (int f = 0; f < 4; ++f)
                    b[f] = *(const s16x8*)&Bs[(wn * 64 + f * 16 + rsel) * 64 + ksel];
                #pragma unroll
                for (int fm = 0; fm < 4; ++fm)
                    #pragma unroll
                    for (int fn = 0; fn < 4; ++fn)
                        acc[fm][fn] = __builtin_amdgcn_mfma_f32_16x16x32_bf16(
                            a[fm], b[fn], acc[fm][fn], 0, 0, 0);
            }
            __syncthreads();
        }
    }
    float bv[4];
    #pragma unroll
    for (int fn = 0; fn < 4; ++fn)
        bv[fn] = bias[wn * 64 + fn * 16 + (lane & 15)];
    #pragma unroll
    for (int fm = 0; fm < 4; ++fm) {
        #pragma unroll
        for (int r = 0; r < 4; ++r) {
            float v = 0.f;
            #pragma unroll
            for (int fn = 0; fn < 4; ++fn)
                v = fmaxf(v, fmaxf(acc[fm][fn][r] + bv[fn], 0.f));
            #pragma unroll
            for (int m = 1; m <= 8; m <<= 1) v = fmaxf(v, __shfl_xor(v, m));
            if ((lane & 15) == 0)
                red[wn][wm * 64 + fm * 16 + (lane >> 4) * 4 + r] = v;
        }
    }
    __syncthreads();
    if (tid < 128) {
        float v = fmaxf(fmaxf(red[0][tid], red[1][tid]),
                        fmaxf(red[2][tid], red[3][tid]));
        att[(size_t)mt * 128 + tid] = v;
    }
}

// ---------------- K4: H partials (bf16 S) ----------------
__global__ __launch_bounds__(256) void k_henc_bf(const u16* __restrict__ Sb,
                                                 const float* __restrict__ att,
                                                 float* __restrict__ part) {
    int b_ = blockIdx.x, tc = blockIdx.y;
    int tid = threadIdx.x;
    int d = tid * 4;
    const u16* Sp = Sb + ((size_t)b_ * Tt + (size_t)tc * 256) * Dd + d;
    const float* ap = att + (size_t)b_ * Tt + (size_t)tc * 256;
    f32x4 acc = {};
    for (int t = 0; t < 256; ++t) {
        float a = ap[t];
        u16x4 s = *(const u16x4*)(Sp + (size_t)t * Dd);
        acc.x += bf2f(s.x) * a;
        acc.y += bf2f(s.y) * a;
        acc.z += bf2f(s.z) * a;
        acc.w += bf2f(s.w) * a;
    }
    *(f32x4*)(part + ((size_t)tc * Bb + b_) * Dd + d) = acc;
}

// ---------------- K4-fallback: f32 S ----------------
__global__ __launch_bounds__(256) void k_henc_f32(const float* __restrict__ S,
                                                  const float* __restrict__ att,
                                                  float* __restrict__ part) {
    int b_ = blockIdx.x, tc = blockIdx.y;
    int tid = threadIdx.x;
    int d = tid * 4;
    const float* Sp = S + ((size_t)b_ * Tt + (size_t)tc * 256) * Dd + d;
    const float* ap = att + (size_t)b_ * Tt + (size_t)tc * 256;
    f32x4 acc = {};
    for (int t = 0; t < 256; ++t) {
        float a = ap[t];
        f32x4 s = *(const f32x4*)(Sp + (size_t)t * Dd);
        acc += s * a;
    }
    *(f32x4*)(part + ((size_t)tc * Bb + b_) * Dd + d) = acc;
}

// ---------------- K5: reduce 8 partials -> d_out ----------------
__global__ __launch_bounds__(256) void k_hred(const float* __restrict__ part,
                                              float* __restrict__ out) {
    int i = blockIdx.x * 256 + threadIdx.x;
    float s = 0.f;
    #pragma unroll
    for (int p = 0; p < 8; ++p) s += part[(size_t)p * (Bb * Dd) + i];
    out[i] = s;
}

extern "C" void kernel_launch(void* const* d_in, const int* in_sizes, int n_in,
                              void* d_out, int out_size, void* d_ws, size_t ws_size,
                              hipStream_t stream) {
    const float* S  = (const float*)d_in[0];
    const float* L  = (const float*)d_in[1];
    const float* W  = (const float*)d_in[2];
    const float* cb = (const float*)d_in[3];
    float* out = (float*)d_out;
    char* ws = (char*)d_ws;

    const size_t GP_B   = (size_t)Bb * TP * Cc * 2;   // 268,959,744
    const size_t LN_B   = (size_t)Cc * Dd * 2;        //   2,097,152
    const size_t WT_B   = (size_t)5 * Ff * Cc * 2;    //   2,621,440
    const size_t ATT_B  = (size_t)M1 * 4;             //     524,288
    const size_t PART_B = (size_t)8 * Bb * Dd * 4;    //   2,097,152
    const size_t SB_B   = (size_t)M1 * Dd * 2;        // 268,435,456
    u16*   Gp   = (u16*)(ws);
    u16*   Ln   = (u16*)(ws + GP_B);
    u16*   Wt   = (u16*)(ws + GP_B + LN_B);
    float* att  = (float*)(ws + GP_B + LN_B + WT_B);
    float* part = (float*)(ws + GP_B + LN_B + WT_B + ATT_B);
    u16*   Sb   = (u16*)(ws + GP_B + LN_B + WT_B + ATT_B + PART_B);
    const bool use_bf = ws_size >= GP_B + LN_B + WT_B + ATT_B + PART_B + SB_B;

    k_label_norm<<<Cc, 256, 0, stream>>>(L, Ln);
    k_wt<<<dim3(5, Cc / 64, Ff / 64), 256, 0, stream>>>(W, Wt);
    k_zpad<<<Bb, 256, 0, stream>>>(Gp);
    if (use_bf) {
        k_s2bf<<<2048, 256, 0, stream>>>(S, Sb);
        k_gemm1_bf<<<(M1 / 128) * (Cc / 128), 256, 0, stream>>>(Sb, Ln, Gp);
    } else {
        k_gemm1_f32<<<(M1 / 128) * (Cc / 128), 256, 0, stream>>>(S, Ln, Gp);
    }
    k_conv<<<M1 / 128, 512, 0, stream>>>(Gp, Wt, cb, att);
    if (use_bf) k_henc_bf<<<dim3(Bb, 8), 256, 0, stream>>>(Sb, att, part);
    else        k_henc_f32<<<dim3(Bb, 8), 256, 0, stream>>>(S, att, part);
    k_hred<<<(Bb * Dd) / 256, 256, 0, stream>>>(part, out);
}

// Round 3
// 946.464 us; speedup vs baseline: 1.3767x; 1.3252x over previous
//
#include <hip/hip_runtime.h>

typedef unsigned short u16;
typedef __attribute__((ext_vector_type(4))) float f32x4;
typedef __attribute__((ext_vector_type(8))) short s16x8;
typedef __attribute__((ext_vector_type(4))) unsigned short u16x4;

#define DEV __device__ __forceinline__

// Problem constants
constexpr int Bb = 64, Tt = 2048, Dd = 1024, Cc = 1024, Ff = 256;
constexpr int TP = Tt + 4;            // padded time (2 halo rows each side)
constexpr int M1 = Bb * Tt;           // 131072

DEV u16 f2bf(float f) {               // RNE f32 -> bf16
    union { float f; unsigned u; } v; v.f = f;
    unsigned r = v.u + 0x7fffu + ((v.u >> 16) & 1u);
    return (u16)(r >> 16);
}
DEV float bf2f(u16 h) {
    union { unsigned u; float f; } v; v.u = ((unsigned)h) << 16; return v.f;
}

// async global->LDS, 16B per lane. lds dest must be wave-uniform base;
// HW writes lane l at base + l*16.
DEV void gl_lds16(const u16* g, u16* l) {
    __builtin_amdgcn_global_load_lds(
        (const __attribute__((address_space(1))) unsigned*)(const void*)g,
        (__attribute__((address_space(3))) unsigned*)(void*)l,
        16, 0, 0);
}

// T2 swizzle helpers (16B-slot XOR within 128B row):
//  - staging lane l loads global col-slot (l&7)^((l>>3)&7)  [inverse swizzle]
//  - ds_read of logical elem-offset e in row r uses e ^ ((r&7)<<3)
DEV int swz_scol(int lane) { return (((lane & 7) ^ ((lane >> 3) & 7)) << 3); }
DEV int swz_rd(int row, int e) { return e ^ ((row & 7) << 3); }

// ---------------- K-1: S f32 -> bf16 ----------------
__global__ __launch_bounds__(256) void k_s2bf(const float* __restrict__ S,
                                              u16* __restrict__ Sb) {
    size_t i = ((size_t)blockIdx.x * 256 + threadIdx.x) * 8;
    const size_t stride = (size_t)gridDim.x * 256 * 8;
    const size_t n = (size_t)M1 * Dd;
    for (; i < n; i += stride) {
        f32x4 a = *(const f32x4*)(S + i);
        f32x4 b = *(const f32x4*)(S + i + 4);
        s16x8 r;
        r[0] = (short)f2bf(a.x); r[1] = (short)f2bf(a.y);
        r[2] = (short)f2bf(a.z); r[3] = (short)f2bf(a.w);
        r[4] = (short)f2bf(b.x); r[5] = (short)f2bf(b.y);
        r[6] = (short)f2bf(b.z); r[7] = (short)f2bf(b.w);
        *(s16x8*)(Sb + i) = r;
    }
}

// ---------------- K0: l2-normalize label rows, cast bf16 ----------------
__global__ __launch_bounds__(256) void k_label_norm(const float* __restrict__ L,
                                                    u16* __restrict__ Ln) {
    int c = blockIdx.x;
    int t = threadIdx.x;
    const float* row = L + (size_t)c * Dd;
    float s = 0.f;
    for (int d = t; d < Dd; d += 256) { float v = row[d]; s += v * v; }
    for (int o = 32; o; o >>= 1) s += __shfl_down(s, o);
    __shared__ float red[4];
    if ((t & 63) == 0) red[t >> 6] = s;
    __syncthreads();
    float tot = red[0] + red[1] + red[2] + red[3];
    float r = rsqrtf(fmaxf(tot, 1e-12f));
    for (int d = t; d < Dd; d += 256) Ln[(size_t)c * Dd + d] = f2bf(row[d] * r);
}

// ---------------- K0b: transpose conv_w (K,C,F) f32 -> Wt (K,F,C) bf16 --
__global__ __launch_bounds__(256) void k_wt(const float* __restrict__ W,
                                            u16* __restrict__ Wt) {
    __shared__ float tile[64][65];
    int k = blockIdx.x; int c0 = blockIdx.y * 64; int f0 = blockIdx.z * 64;
    int tid = threadIdx.x;
    const float* Wk = W + (size_t)k * Cc * Ff;
    #pragma unroll
    for (int i = 0; i < 16; ++i) {
        int q = tid + i * 256;
        int ci = q >> 6, fj = q & 63;
        tile[ci][fj] = Wk[(size_t)(c0 + ci) * Ff + f0 + fj];
    }
    __syncthreads();
    #pragma unroll
    for (int i = 0; i < 16; ++i) {
        int q = tid + i * 256;
        int fi = q >> 6, cj = q & 63;
        Wt[((size_t)k * Ff + f0 + fi) * Cc + c0 + cj] = f2bf(tile[cj][fi]);
    }
}

// ---------------- K1: zero the halo rows of padded G ----------------
__global__ __launch_bounds__(256) void k_zpad(u16* __restrict__ Gp) {
    int b_ = blockIdx.x, tid = threadIdx.x;
    size_t base = (size_t)b_ * TP * Cc;
    for (int i = tid; i < 2 * Cc; i += 256) {
        Gp[base + i] = 0;
        Gp[base + (size_t)(TP - 2) * Cc + i] = 0;
    }
}

// ---------------- K2: G = Sb(bf16) @ Ln^T  -> Gp bf16 (padded rows) -----
// 128x128, BK=64, 4 waves (2x2), global_load_lds staging (T2-swizzled),
// XCD-chunked grid.
__global__ __launch_bounds__(256) void k_gemm1_bf(const u16* __restrict__ Sb,
                                                  const u16* __restrict__ Ln,
                                                  u16* __restrict__ Gp) {
    __shared__ alignas(16) u16 As[128 * 64];
    __shared__ alignas(16) u16 Bs[128 * 64];
    int bid = blockIdx.x;
    // XCD chunking: xcd = bid&7 gets wgs [xcd*1024, ...): 128 mt x 8 nt, mt-major
    int xcd = bid & 7, idx = bid >> 3;
    int mt = xcd * 128 + (idx >> 3);
    int nt = idx & 7;
    const int m0 = mt * 128, n0 = nt * 128;
    int tid = threadIdx.x;
    int lane = tid & 63, wid = tid >> 6;
    int wm = wid >> 1, wn = wid & 1;
    int srow = lane >> 3;             // staging: lane -> row-in-segment
    int scol = swz_scol(lane);        // staging: lane -> col (pre-swizzled)
    f32x4 acc[4][4] = {};

    for (int kt = 0; kt < 16; ++kt) {
        int k0 = kt * 64;
        #pragma unroll
        for (int i = 0; i < 4; ++i) {
            int seg = wid * 4 + i;    // 0..15, 8 rows each
            int r0 = seg * 8;
            gl_lds16(Sb + (size_t)(m0 + r0 + srow) * Dd + k0 + scol, &As[seg * 512]);
            gl_lds16(Ln + (size_t)(n0 + r0 + srow) * Dd + k0 + scol, &Bs[seg * 512]);
        }
        __syncthreads();
        #pragma unroll
        for (int kk = 0; kk < 2; ++kk) {
            int rsel = lane & 15, ksel = kk * 32 + (lane >> 4) * 8;
            s16x8 a[4], b[4];
            #pragma unroll
            for (int f = 0; f < 4; ++f) {
                int row = wm * 64 + f * 16 + rsel;
                a[f] = *(const s16x8*)&As[row * 64 + swz_rd(row, ksel)];
            }
            #pragma unroll
            for (int f = 0; f < 4; ++f) {
                int row = wn * 64 + f * 16 + rsel;
                b[f] = *(const s16x8*)&Bs[row * 64 + swz_rd(row, ksel)];
            }
            #pragma unroll
            for (int fm = 0; fm < 4; ++fm)
                #pragma unroll
                for (int fn = 0; fn < 4; ++fn)
                    acc[fm][fn] = __builtin_amdgcn_mfma_f32_16x16x32_bf16(
                        a[fm], b[fn], acc[fm][fn], 0, 0, 0);
        }
        __syncthreads();
    }
    #pragma unroll
    for (int fm = 0; fm < 4; ++fm) {
        #pragma unroll
        for (int r = 0; r < 4; ++r) {
            int row = m0 + wm * 64 + fm * 16 + (lane >> 4) * 4 + r;
            int b_ = row >> 11, t = row & 2047;
            size_t base = ((size_t)b_ * TP + t + 2) * Cc;
            #pragma unroll
            for (int fn = 0; fn < 4; ++fn) {
                int col = n0 + wn * 64 + fn * 16 + (lane & 15);
                Gp[base + col] = f2bf(acc[fm][fn][r]);
            }
        }
    }
}

// ---------------- K2-fallback: f32 A path (linear LDS, consistent) ------
__global__ __launch_bounds__(256) void k_gemm1_f32(const float* __restrict__ S,
                                                   const u16* __restrict__ Ln,
                                                   u16* __restrict__ Gp) {
    __shared__ alignas(16) u16 As[128 * 64];
    __shared__ alignas(16) u16 Bs[128 * 64];
    int bid = blockIdx.x;
    int xcd = bid & 7, idx = bid >> 3;
    int mt = xcd * 128 + (idx >> 3);
    int nt = idx & 7;
    const int m0 = mt * 128, n0 = nt * 128;
    int tid = threadIdx.x;
    int lane = tid & 63, wid = tid >> 6;
    int wm = wid >> 1, wn = wid & 1;
    f32x4 acc[4][4] = {};

    for (int kt = 0; kt < 16; ++kt) {
        int k0 = kt * 64;
        #pragma unroll
        for (int i = 0; i < 8; ++i) {
            int q = tid + i * 256;
            int row = q >> 4, c4 = (q & 15) * 4;
            f32x4 v = *(const f32x4*)(S + (size_t)(m0 + row) * Dd + k0 + c4);
            u16* p = &As[row * 64 + c4];
            p[0] = f2bf(v.x); p[1] = f2bf(v.y); p[2] = f2bf(v.z); p[3] = f2bf(v.w);
        }
        #pragma unroll
        for (int i = 0; i < 4; ++i) {
            int q = tid + i * 256;
            int row = q >> 3, c8 = (q & 7) * 8;
            *(s16x8*)&Bs[row * 64 + c8] =
                *(const s16x8*)(Ln + (size_t)(n0 + row) * Dd + k0 + c8);
        }
        __syncthreads();
        #pragma unroll
        for (int kk = 0; kk < 2; ++kk) {
            int rsel = lane & 15, ksel = kk * 32 + (lane >> 4) * 8;
            s16x8 a[4], b[4];
            #pragma unroll
            for (int f = 0; f < 4; ++f)
                a[f] = *(const s16x8*)&As[(wm * 64 + f * 16 + rsel) * 64 + ksel];
            #pragma unroll
            for (int f = 0; f < 4; ++f)
                b[f] = *(const s16x8*)&Bs[(wn * 64 + f * 16 + rsel) * 64 + ksel];
            #pragma unroll
            for (int fm = 0; fm < 4; ++fm)
                #pragma unroll
                for (int fn = 0; fn < 4; ++fn)
                    acc[fm][fn] = __builtin_amdgcn_mfma_f32_16x16x32_bf16(
                        a[fm], b[fn], acc[fm][fn], 0, 0, 0);
        }
        __syncthreads();
    }
    #pragma unroll
    for (int fm = 0; fm < 4; ++fm) {
        #pragma unroll
        for (int r = 0; r < 4; ++r) {
            int row = m0 + wm * 64 + fm * 16 + (lane >> 4) * 4 + r;
            int b_ = row >> 11, t = row & 2047;
            size_t base = ((size_t)b_ * TP + t + 2) * Cc;
            #pragma unroll
            for (int fn = 0; fn < 4; ++fn) {
                int col = n0 + wn * 64 + fn * 16 + (lane & 15);
                Gp[base + col] = f2bf(acc[fm][fn][r]);
            }
        }
    }
}

// ---------------- K3: conv1d(K=5) as GEMM + relu + max_f -> att_v -------
// BM=128, BN=256 (full F), 8 waves (2x4), gl_lds staging (T2-swizzled).
__global__ __launch_bounds__(512) void k_conv(const u16* __restrict__ Gp,
                                              const u16* __restrict__ Wt,
                                              const float* __restrict__ bias,
                                              float* __restrict__ att) {
    __shared__ alignas(16) u16 As[136 * 64];   // rows 132..135 = overrun garbage, never consumed
    __shared__ alignas(16) u16 Bs[256 * 64];
    __shared__ float red[4][128];
    int mt = blockIdx.x;
    int b_ = mt >> 4;
    int t0 = (mt & 15) * 128;
    int tid = threadIdx.x, lane = tid & 63, wid = tid >> 6;
    int wm = wid >> 2, wn = wid & 3;
    int srow = lane >> 3, scol = swz_scol(lane);
    f32x4 acc[4][4] = {};
    const size_t gbase = ((size_t)b_ * TP + t0) * Cc;

    for (int ct = 0; ct < 16; ++ct) {
        int c0 = ct * 64;
        // A: 17 segments of 8 rows (136 rows incl. 4 garbage)
        for (int s = wid; s < 17; s += 8)
            gl_lds16(Gp + gbase + (size_t)(s * 8 + srow) * Cc + c0 + scol, &As[s * 512]);
        for (int k = 0; k < 5; ++k) {
            #pragma unroll
            for (int i = 0; i < 4; ++i) {
                int seg = wid * 4 + i;    // 0..31
                gl_lds16(Wt + ((size_t)k * Ff + seg * 8 + srow) * Cc + c0 + scol,
                         &Bs[seg * 512]);
            }
            __syncthreads();
            #pragma unroll
            for (int kk = 0; kk < 2; ++kk) {
                int rsel = lane & 15, ksel = kk * 32 + (lane >> 4) * 8;
                s16x8 a[4], b[4];
                #pragma unroll
                for (int f = 0; f < 4; ++f) {
                    int row = k + wm * 64 + f * 16 + rsel;
                    a[f] = *(const s16x8*)&As[row * 64 + swz_rd(row, ksel)];
                }
                #pragma unroll
                for (int f = 0; f < 4; ++f) {
                    int row = wn * 64 + f * 16 + rsel;
                    b[f] = *(const s16x8*)&Bs[row * 64 + swz_rd(row, ksel)];
                }
                #pragma unroll
                for (int fm = 0; fm < 4; ++fm)
                    #pragma unroll
                    for (int fn = 0; fn < 4; ++fn)
                        acc[fm][fn] = __builtin_amdgcn_mfma_f32_16x16x32_bf16(
                            a[fm], b[fn], acc[fm][fn], 0, 0, 0);
            }
            __syncthreads();
        }
    }
    float bv[4];
    #pragma unroll
    for (int fn = 0; fn < 4; ++fn)
        bv[fn] = bias[wn * 64 + fn * 16 + (lane & 15)];
    #pragma unroll
    for (int fm = 0; fm < 4; ++fm) {
        #pragma unroll
        for (int r = 0; r < 4; ++r) {
            float v = 0.f;
            #pragma unroll
            for (int fn = 0; fn < 4; ++fn)
                v = fmaxf(v, fmaxf(acc[fm][fn][r] + bv[fn], 0.f));
            #pragma unroll
            for (int m = 1; m <= 8; m <<= 1) v = fmaxf(v, __shfl_xor(v, m));
            if ((lane & 15) == 0)
                red[wn][wm * 64 + fm * 16 + (lane >> 4) * 4 + r] = v;
        }
    }
    __syncthreads();
    if (tid < 128) {
        float v = fmaxf(fmaxf(red[0][tid], red[1][tid]),
                        fmaxf(red[2][tid], red[3][tid]));
        att[(size_t)mt * 128 + tid] = v;
    }
}

// ---------------- K4: H partials (bf16 S) ----------------
__global__ __launch_bounds__(256) void k_henc_bf(const u16* __restrict__ Sb,
                                                 const float* __restrict__ att,
                                                 float* __restrict__ part) {
    int b_ = blockIdx.x, tc = blockIdx.y;
    int tid = threadIdx.x;
    int d = tid * 4;
    const u16* Sp = Sb + ((size_t)b_ * Tt + (size_t)tc * 256) * Dd + d;
    const float* ap = att + (size_t)b_ * Tt + (size_t)tc * 256;
    f32x4 acc = {};
    for (int t = 0; t < 256; ++t) {
        float a = ap[t];
        u16x4 s = *(const u16x4*)(Sp + (size_t)t * Dd);
        acc.x += bf2f(s.x) * a;
        acc.y += bf2f(s.y) * a;
        acc.z += bf2f(s.z) * a;
        acc.w += bf2f(s.w) * a;
    }
    *(f32x4*)(part + ((size_t)tc * Bb + b_) * Dd + d) = acc;
}

// ---------------- K4-fallback: f32 S ----------------
__global__ __launch_bounds__(256) void k_henc_f32(const float* __restrict__ S,
                                                  const float* __restrict__ att,
                                                  float* __restrict__ part) {
    int b_ = blockIdx.x, tc = blockIdx.y;
    int tid = threadIdx.x;
    int d = tid * 4;
    const float* Sp = S + ((size_t)b_ * Tt + (size_t)tc * 256) * Dd + d;
    const float* ap = att + (size_t)b_ * Tt + (size_t)tc * 256;
    f32x4 acc = {};
    for (int t = 0; t < 256; ++t) {
        float a = ap[t];
        f32x4 s = *(const f32x4*)(Sp + (size_t)t * Dd);
        acc += s * a;
    }
    *(f32x4*)(part + ((size_t)tc * Bb + b_) * Dd + d) = acc;
}

// ---------------- K5: reduce 8 partials -> d_out ----------------
__global__ __launch_bounds__(256) void k_hred(const float* __restrict__ part,
                                              float* __restrict__ out) {
    int i = blockIdx.x * 256 + threadIdx.x;
    float s = 0.f;
    #pragma unroll
    for (int p = 0; p < 8; ++p) s += part[(size_t)p * (Bb * Dd) + i];
    out[i] = s;
}

extern "C" void kernel_launch(void* const* d_in, const int* in_sizes, int n_in,
                              void* d_out, int out_size, void* d_ws, size_t ws_size,
                              hipStream_t stream) {
    const float* S  = (const float*)d_in[0];
    const float* L  = (const float*)d_in[1];
    const float* W  = (const float*)d_in[2];
    const float* cb = (const float*)d_in[3];
    float* out = (float*)d_out;
    char* ws = (char*)d_ws;

    const size_t GP_B   = (size_t)Bb * TP * Cc * 2;   // 268,959,744
    const size_t LN_B   = (size_t)Cc * Dd * 2;        //   2,097,152
    const size_t WT_B   = (size_t)5 * Ff * Cc * 2;    //   2,621,440
    const size_t ATT_B  = (size_t)M1 * 4;             //     524,288
    const size_t PART_B = (size_t)8 * Bb * Dd * 4;    //   2,097,152
    const size_t SB_B   = (size_t)M1 * Dd * 2;        // 268,435,456
    u16*   Gp   = (u16*)(ws);
    u16*   Ln   = (u16*)(ws + GP_B);
    u16*   Wt   = (u16*)(ws + GP_B + LN_B);
    float* att  = (float*)(ws + GP_B + LN_B + WT_B);
    float* part = (float*)(ws + GP_B + LN_B + WT_B + ATT_B);
    u16*   Sb   = (u16*)(ws + GP_B + LN_B + WT_B + ATT_B + PART_B);
    const bool use_bf = ws_size >= GP_B + LN_B + WT_B + ATT_B + PART_B + SB_B;

    k_label_norm<<<Cc, 256, 0, stream>>>(L, Ln);
    k_wt<<<dim3(5, Cc / 64, Ff / 64), 256, 0, stream>>>(W, Wt);
    k_zpad<<<Bb, 256, 0, stream>>>(Gp);
    if (use_bf) {
        k_s2bf<<<2048, 256, 0, stream>>>(S, Sb);
        k_gemm1_bf<<<(M1 / 128) * (Cc / 128), 256, 0, stream>>>(Sb, Ln, Gp);
    } else {
        k_gemm1_f32<<<(M1 / 128) * (Cc / 128), 256, 0, stream>>>(S, Ln, Gp);
    }
    k_conv<<<M1 / 128, 512, 0, stream>>>(Gp, Wt, cb, att);
    if (use_bf) k_henc_bf<<<dim3(Bb, 8), 256, 0, stream>>>(Sb, att, part);
    else        k_henc_f32<<<dim3(Bb, 8), 256, 0, stream>>>(S, att, part);
    k_hred<<<(Bb * Dd) / 256, 256, 0, stream>>>(part, out);
}